// Round 8
// baseline (181.161 us; speedup 1.0000x reference)
//
#include <hip/hip_runtime.h>

#define BATCH 8
#define SEQ   2048
#define EMB   1024
#define HD    64
#define HEADS 16
#define LOG2E 1.4426950408889634f

typedef _Float16 half8  __attribute__((ext_vector_type(8)));
typedef short    short8v __attribute__((ext_vector_type(8)));
typedef short    short4v __attribute__((ext_vector_type(4)));
typedef float    f32x4  __attribute__((ext_vector_type(4)));

__device__ __forceinline__ float fexp2(float x) { return __builtin_amdgcn_exp2f(x); }

__device__ __forceinline__ short f2bf(float f) {   // f32 -> bf16 bits (RNE)
    union { float f; unsigned u; } x; x.f = f;
    unsigned r = x.u + 0x7fffu + ((x.u >> 16) & 1u);
    return (short)(r >> 16);
}
__device__ __forceinline__ float bf2f(short s) {
    union { unsigned u; float f; } x; x.u = ((unsigned)(unsigned short)s) << 16;
    return x.f;
}

// async global->LDS DMA, 16B/lane; lds base wave-uniform
__device__ __forceinline__ void dma16(void* lds, const void* g) {
    __builtin_amdgcn_global_load_lds(
        (const __attribute__((address_space(1))) unsigned int*)g,
        (__attribute__((address_space(3))) unsigned int*)lds, 16, 0, 0);
}

// Fine-grained pipeline control: wait until <= N of THIS wave's vmem ops
// outstanding, then (optionally) raw barrier. asm memory clobber = compiler
// fence so DMA/ds ops can't migrate across.
#define WAIT_BARRIER(N) asm volatile("s_waitcnt vmcnt(" #N ")\ns_barrier" ::: "memory")
#define WAITVM(N)       asm volatile("s_waitcnt vmcnt(" #N ")" ::: "memory")

// ---------------- W -> fp16 (Wq pre-scaled by log2e: scores in log2 domain)
__global__ __launch_bounds__(256) void wcvt_kernel(
    const float* __restrict__ Wq, const float* __restrict__ Wk,
    const float* __restrict__ Wv, _Float16* __restrict__ Wh)
{
    const int m = blockIdx.y;
    const float* src = (m == 0) ? Wq : (m == 1) ? Wk : Wv;
    const float scale = (m == 0) ? LOG2E : 1.0f;
    const int idx = (blockIdx.x * 256 + threadIdx.x) * 8;
    float4 f0 = *(const float4*)(src + idx);
    float4 f1 = *(const float4*)(src + idx + 4);
    half8 h;
    h[0] = (_Float16)(f0.x * scale); h[1] = (_Float16)(f0.y * scale);
    h[2] = (_Float16)(f0.z * scale); h[3] = (_Float16)(f0.w * scale);
    h[4] = (_Float16)(f1.x * scale); h[5] = (_Float16)(f1.y * scale);
    h[6] = (_Float16)(f1.z * scale); h[7] = (_Float16)(f1.w * scale);
    *(half8*)(Wh + (size_t)m * 65536 + idx) = h;
}

// ---------------- QKV projection ----------------
// 512 blocks x 512 thr (8 waves). Block = 32 rows; wave: strip=(w&1) rows,
// grp=(w>>1) -> 3 of 12 ctiles. 32 k-chunks of 32; x(f32)+W(fp16) staged by
// DMA into 3 buffers; J=2 DMA/wave/chunk -> steady wait vmcnt(2).
__global__ __launch_bounds__(512, 4) void qkv_kernel(
    const float* __restrict__ x, const _Float16* __restrict__ Wh,
    _Float16* __restrict__ qh, _Float16* __restrict__ kh, short* __restrict__ vpt)
{
    __shared__ __align__(16) char arena[49152];   // 3 x (x 4KB | W 12KB)
    const int t = threadIdx.x, lane = t & 63, wave = t >> 6;
    const int l15 = lane & 15, quad = lane >> 4;
    const int strip = wave & 1, grp = wave >> 1;
    const int row0 = blockIdx.x * 32;

    auto issue = [&](int buf, int k0) {
        char* base = arena + buf * 16384;
        #pragma unroll
        for (int jj = 0; jj < 2; ++jj) {
            const int j = wave * 2 + jj;
            if (j < 4) {        // x: [32 rows][32 f32], granule swizzle ^(row&7)
                const int row = j * 8 + (lane >> 3);
                const int logi = (lane & 7) ^ (lane >> 3);
                dma16(base + j * 1024,
                      x + (size_t)(row0 + row) * EMB + k0 + logi * 4);
            } else {            // W: [192 d][32 halves], granule (g+(d>>1))&3
                const int jw = j - 4;
                const int dd = jw * 16 + (lane >> 2);
                const int logi = ((lane & 3) - ((lane >> 3) & 3)) & 3;
                dma16(base + 4096 + jw * 1024,
                      Wh + (size_t)(dd >> 6) * 65536 + (size_t)(dd & 63) * EMB
                         + k0 + logi * 8);
            }
        }
    };

    issue(0, 0);
    issue(1, 32);

    f32x4 acc[3] = {};
    const int xrow = strip * 16 + l15;
    for (int it = 0; it < 32; ++it) {
        if (it < 31) { WAIT_BARRIER(2); } else { WAIT_BARRIER(0); }
        if (it + 2 < 32) issue((it + 2) % 3, (it + 2) * 32);
        const int buf = it % 3;
        const float* xb = (const float*)(arena + buf * 16384);
        const _Float16* wb = (const _Float16*)(arena + buf * 16384 + 4096);
        f32x4 u0 = *(const f32x4*)(xb + xrow * 32 + (((quad * 2)     ^ (l15 & 7)) * 4));
        f32x4 u1 = *(const f32x4*)(xb + xrow * 32 + (((quad * 2 + 1) ^ (l15 & 7)) * 4));
        half8 a;
        a[0] = (_Float16)u0[0]; a[1] = (_Float16)u0[1];
        a[2] = (_Float16)u0[2]; a[3] = (_Float16)u0[3];
        a[4] = (_Float16)u1[0]; a[5] = (_Float16)u1[1];
        a[6] = (_Float16)u1[2]; a[7] = (_Float16)u1[3];
        #pragma unroll
        for (int j = 0; j < 3; ++j) {
            const int dd = (grp * 3 + j) * 16 + l15;
            half8 bfr = *(const half8*)(wb + dd * 32 + (((quad + (dd >> 1)) & 3) * 8));
            acc[j] = __builtin_amdgcn_mfma_f32_16x16x32_f16(a, bfr, acc[j], 0, 0, 0);
        }
    }

    #pragma unroll
    for (int j = 0; j < 3; ++j) {
        const int c = grp * 3 + j, m = c >> 2, n = c & 3;
        if (m < 2) {
            _Float16* __restrict__ dst = (m == 0) ? qh : kh;
            #pragma unroll
            for (int r = 0; r < 4; ++r)
                dst[(size_t)(row0 + strip * 16 + quad * 4 + r) * HD + n * 16 + l15] =
                    (_Float16)acc[j][r];
        } else {   // v transposed bf16: vpt[b][d][s]
            const int rg = row0 + strip * 16 + quad * 4;
            const int b = rg >> 11, s = rg & 2047;
            short4v h;
            h[0] = f2bf(acc[j][0]); h[1] = f2bf(acc[j][1]);
            h[2] = f2bf(acc[j][2]); h[3] = f2bf(acc[j][3]);
            *(short4v*)(vpt + ((size_t)b * HD + n * 16 + l15) * SEQ + s) = h;
        }
    }
}

// ---------------- Column-softmax denominators + v pre-scale ----------------
// grid (64,8) x 256 (4 waves). Block = 32 keys (A-frags in regs). Wave w sweeps
// its private queries [w*512,(w+1)*512) in 16 chunks of 32, wave-private
// triple-buffered DMA (J=4), NO barriers in the loop. Afterwards the block
// scales vpt[b][:, c0..c0+31] by 1/colsum in place (bf16).
__global__ __launch_bounds__(256, 2) void stats_kernel(
    const _Float16* __restrict__ qh, const _Float16* __restrict__ kh,
    short* __restrict__ vpt)
{
    __shared__ __align__(16) char arena[49152];   // 4 waves x 3 bufs x 4KB
    __shared__ float red[4][32];
    __shared__ float linv_s[32];
    const int t = threadIdx.x, lane = t & 63, wave = t >> 6;
    const int l15 = lane & 15, quad = lane >> 4;
    const int b = blockIdx.y, c0 = blockIdx.x * 32;

    half8 ka[2][2];
    #pragma unroll
    for (int kt = 0; kt < 2; ++kt) {
        const _Float16* kp = kh + ((size_t)b * SEQ + c0 + kt * 16 + l15) * HD + quad * 8;
        ka[kt][0] = *(const half8*)(kp);
        ka[kt][1] = *(const half8*)(kp + 32);
    }

    char* mybase = arena + wave * 12288;
    auto issue = [&](int buf, int q0) {
        #pragma unroll
        for (int j = 0; j < 4; ++j) {
            const int qq = j * 8 + (lane >> 3);
            const int logi = (lane & 7) ^ (lane >> 3);
            dma16(mybase + buf * 4096 + j * 1024,
                  qh + ((size_t)b * SEQ + q0 + qq) * HD + logi * 8);
        }
    };

    const int q0w = wave * 512;
    issue(0, q0w);
    issue(1, q0w + 32);

    float csum[2][4] = {};
    for (int it = 0; it < 16; ++it) {
        if (it < 15) { WAITVM(4); } else { WAITVM(0); }
        if (it + 2 < 16) issue((it + 2) % 3, q0w + (it + 2) * 32);
        const _Float16* qb = (const _Float16*)(mybase + (it % 3) * 4096);
        #pragma unroll
        for (int qt = 0; qt < 2; ++qt) {
            half8 bq[2];
            #pragma unroll
            for (int kc = 0; kc < 2; ++kc)
                bq[kc] = *(const half8*)(qb + (qt * 16 + l15) * 64
                           + (((kc * 4 + quad) ^ (l15 & 7)) * 8));
            f32x4 s0 = {}, s1 = {};
            s0 = __builtin_amdgcn_mfma_f32_16x16x32_f16(ka[0][0], bq[0], s0, 0, 0, 0);
            s0 = __builtin_amdgcn_mfma_f32_16x16x32_f16(ka[0][1], bq[1], s0, 0, 0, 0);
            s1 = __builtin_amdgcn_mfma_f32_16x16x32_f16(ka[1][0], bq[0], s1, 0, 0, 0);
            s1 = __builtin_amdgcn_mfma_f32_16x16x32_f16(ka[1][1], bq[1], s1, 0, 0, 0);
            #pragma unroll
            for (int r = 0; r < 4; ++r) {
                csum[0][r] += fexp2(s0[r]);
                csum[1][r] += fexp2(s1[r]);
            }
        }
    }
    #pragma unroll
    for (int kt = 0; kt < 2; ++kt)
        #pragma unroll
        for (int r = 0; r < 4; ++r) {
            csum[kt][r] += __shfl_xor(csum[kt][r], 1);
            csum[kt][r] += __shfl_xor(csum[kt][r], 2);
            csum[kt][r] += __shfl_xor(csum[kt][r], 4);
            csum[kt][r] += __shfl_xor(csum[kt][r], 8);
        }
    if (l15 == 0) {
        #pragma unroll
        for (int kt = 0; kt < 2; ++kt)
            #pragma unroll
            for (int r = 0; r < 4; ++r)
                red[wave][kt * 16 + quad * 4 + r] = csum[kt][r];
    }
    __syncthreads();
    if (t < 32)
        linv_s[t] = 1.0f / (red[0][t] + red[1][t] + red[2][t] + red[3][t]);
    __syncthreads();
    // scale vpt[b][d][c0..c0+31] in place: ṽ = v * l_inv (bf16)
    {
        const int d = t >> 2, sg = (t & 3) * 8;
        short* vp = vpt + ((size_t)b * HD + d) * SEQ + c0 + sg;
        short8v vv = *(short8v*)vp, ro;
        #pragma unroll
        for (int j = 0; j < 8; ++j)
            ro[j] = f2bf(bf2f(vv[j]) * linv_s[sg + j]);
        *(short8v*)vp = ro;
    }
}

// ---------------- out = P~ @ ṽ, P~ = exp2(s~) (bf16, up to 2^68) ----------
// grid (64,8) x 256 (4 waves): rw=(w&1) row-tile, kw=(w>>1) key-half.
// Block = 32 q-rows; 32 chunks of 64 keys; k(fp16)+ṽ(bf16) DMA'd into 3
// buffers, J=4/wave -> steady wait vmcnt(4) + raw barrier (prefetch survives).
__global__ __launch_bounds__(256, 2) void out_kernel(
    const _Float16* __restrict__ qh, const _Float16* __restrict__ kh,
    const short* __restrict__ vpt, float* __restrict__ out)
{
    __shared__ __align__(16) char arena[54272];
    // bufs: 3 x 16KB: [k 8KB | ṽ 8KB]; ps at 49152: 4 waves x [16][40] shorts
    const int t = threadIdx.x, lane = t & 63, wave = t >> 6;
    const int l15 = lane & 15, quad = lane >> 4;
    const int rw = wave & 1, kw = wave >> 1;
    const int b = blockIdx.y, r0 = blockIdx.x * 32;

    half8 aq[2];
    {
        const _Float16* qp = qh + ((size_t)b * SEQ + r0 + rw * 16 + l15) * HD + quad * 8;
        aq[0] = *(const half8*)(qp);
        aq[1] = *(const half8*)(qp + 32);
    }

    auto issue = [&](int buf, int c0) {
        char* base = arena + buf * 16384;
        #pragma unroll
        for (int jj = 0; jj < 4; ++jj) {
            const int j = wave * 4 + jj;
            const int logi = (lane & 7) ^ (lane >> 3);
            if (j < 8) {        // k: [64 keys][64 halves]
                const int key = j * 8 + (lane >> 3);
                dma16(base + j * 1024,
                      kh + ((size_t)b * SEQ + c0 + key) * HD + logi * 8);
            } else {            // ṽ: [64 d][64 keys] bf16
                const int jv = j - 8;
                const int d = jv * 8 + (lane >> 3);
                dma16(base + 8192 + jv * 1024,
                      vpt + ((size_t)b * HD + d) * SEQ + c0 + logi * 8);
            }
        }
    };

    issue(0, 0);
    issue(1, 64);

    short* psb = (short*)(arena + 49152) + wave * 640;
    f32x4 oacc[4] = {};
    for (int it = 0; it < 32; ++it) {
        if (it < 31) { WAIT_BARRIER(4); } else { WAIT_BARRIER(0); }
        if (it + 2 < 32) issue((it + 2) % 3, (it + 2) * 64);
        const int buf = it % 3;
        const _Float16* kb = (const _Float16*)(arena + buf * 16384);
        const short* vb = (const short*)(arena + buf * 16384 + 8192);

        f32x4 s[2] = {};
        #pragma unroll
        for (int ct = 0; ct < 2; ++ct) {
            const int key = kw * 32 + ct * 16 + l15;
            #pragma unroll
            for (int kc = 0; kc < 2; ++kc) {
                half8 kf = *(const half8*)(kb + key * 64
                             + (((kc * 4 + quad) ^ (l15 & 7)) * 8));
                s[ct] = __builtin_amdgcn_mfma_f32_16x16x32_f16(aq[kc], kf, s[ct], 0, 0, 0);
            }
        }
        #pragma unroll
        for (int ct = 0; ct < 2; ++ct)
            #pragma unroll
            for (int r = 0; r < 4; ++r)
                psb[(quad * 4 + r) * 40 + ct * 16 + l15] = f2bf(fexp2(s[ct][r]));
        short8v pa = *(const short8v*)(psb + l15 * 40 + quad * 8);
        #pragma unroll
        for (int n = 0; n < 4; ++n) {
            const int d = n * 16 + l15;
            short8v vf = *(const short8v*)(vb + d * 64
                           + (((kw * 4 + quad) ^ (l15 & 7)) * 8));
            oacc[n] = __builtin_amdgcn_mfma_f32_16x16x32_bf16(pa, vf, oacc[n], 0, 0, 0);
        }
    }
    __syncthreads();

    // reduce the two key-half waves per row-tile; overlay staging LDS
    float* red = (float*)arena;               // [32][68]
    float* fin = (float*)(arena + 8704);      // [32][68]
    if (kw == 1) {
        #pragma unroll
        for (int n = 0; n < 4; ++n)
            #pragma unroll
            for (int r = 0; r < 4; ++r)
                red[(rw * 16 + quad * 4 + r) * 68 + n * 16 + l15] = oacc[n][r];
    }
    __syncthreads();
    if (kw == 0) {
        #pragma unroll
        for (int n = 0; n < 4; ++n)
            #pragma unroll
            for (int r = 0; r < 4; ++r)
                fin[(rw * 16 + quad * 4 + r) * 68 + n * 16 + l15] =
                    oacc[n][r] + red[(rw * 16 + quad * 4 + r) * 68 + n * 16 + l15];
    }
    __syncthreads();

    // epilogue: 32x64 f32 tile -> 16 head slots, coalesced float4
    const int row = t >> 3, s8 = t & 7;
    float4 u0 = *(float4*)(fin + row * 68 + s8 * 8);
    float4 u1 = *(float4*)(fin + row * 68 + s8 * 8 + 4);
    size_t base = ((size_t)b * SEQ + r0 + row) * (HD * HEADS);
    #pragma unroll
    for (int h = 0; h < HEADS; ++h) {
        *(float4*)&out[base + h * HD + s8 * 8]     = u0;
        *(float4*)&out[base + h * HD + s8 * 8 + 4] = u1;
    }
}

extern "C" void kernel_launch(void* const* d_in, const int* in_sizes, int n_in,
                              void* d_out, int out_size, void* d_ws, size_t ws_size,
                              hipStream_t stream)
{
    const float* x  = (const float*)d_in[0];
    const float* Wq = (const float*)d_in[1];
    const float* Wk = (const float*)d_in[2];
    const float* Wv = (const float*)d_in[3];
    float* out = (float*)d_out;

    const size_t N = (size_t)BATCH * SEQ * HD;   // 1,048,576
    _Float16* qh  = (_Float16*)d_ws;
    _Float16* kh  = qh + N;
    short*    vpt = (short*)(kh + N);            // bf16 ṽ (scaled in stats)
    _Float16* Wh  = (_Float16*)(vpt + N);        // 196608 halves

    wcvt_kernel <<<dim3(32, 3), 256, 0, stream>>>(Wq, Wk, Wv, Wh);
    qkv_kernel  <<<dim3(512),   512, 0, stream>>>(x, Wh, qh, kh, vpt);
    stats_kernel<<<dim3(64, 8), 256, 0, stream>>>(qh, kh, vpt);
    out_kernel  <<<dim3(64, 8), 256, 0, stream>>>(qh, kh, vpt, out);
}